// Round 9
// baseline (188.182 us; speedup 1.0000x reference)
//
#include <hip/hip_runtime.h>

#define TREES 64
#define NN 63        // internal nodes per tree
#define LL 64        // leaves per tree
#define CC 100       // classes
#define CPAD 112     // classes padded to 7*16
#define DD 512       // feature dim
#define BB 8192      // batch

typedef __attribute__((ext_vector_type(8))) _Float16 f16x8;
typedef __attribute__((ext_vector_type(4))) _Float16 f16x4;
typedef __attribute__((ext_vector_type(4))) float floatx4;

// ---- workspace layout (bytes); ws_size ~= 256 MiB ----
#define XH_WS   0            // x  tiled: [64 rb][8 kt][128 row][8 c][8] f16 = 8 MB
#define SWH_WS  8388608      // sw tiled: [32 cb][8 kt][128 col][8 c][8] f16 = 4 MB
#define W2T_WS  12582912     // [64 t][112 c][64 l] f16 (chunk-swizzled) = 0.92 MB
#define LP_WS   13500416     // [64 t][8192 row][64 l] f16 (chunk-swizzled) = 67 MB

__device__ __forceinline__ void gl_lds16(const _Float16* g, char* lds) {
    __builtin_amdgcn_global_load_lds(
        (const __attribute__((address_space(1))) unsigned int*)g,
        (__attribute__((address_space(3))) unsigned int*)lds, 16, 0, 0);
}

__device__ __forceinline__ f16x8 cvt8(const float* s) {
    float4 a = *(const float4*)s, b = *(const float4*)(s + 4);
    f16x8 h;
    h[0]=(_Float16)a.x; h[1]=(_Float16)a.y; h[2]=(_Float16)a.z; h[3]=(_Float16)a.w;
    h[4]=(_Float16)b.x; h[5]=(_Float16)b.y; h[6]=(_Float16)b.z; h[7]=(_Float16)b.w;
    return h;
}

// fast sigmoid: rcp is 1-ulp; result is rounded to f16 anyway
__device__ __forceinline__ float fsig(float x) {
    return __builtin_amdgcn_rcpf(1.f + __expf(-x));
}

// ---------------------------------------------------------------------------
// Prep (merged): blocks 0..3071 tile+convert x/sw; blocks 3072..4095 build
// w2T[t][c][l'] with leaf chunk pre-swizzled (l' = ((l>>3)^(c&7))*8 + (l&7)).
// ---------------------------------------------------------------------------
__global__ __launch_bounds__(256) void prep_kernel(
    const float* __restrict__ x, const float* __restrict__ sw,
    const float* __restrict__ leaf_logits, const float* __restrict__ tree_w,
    _Float16* __restrict__ xh, _Float16* __restrict__ swh,
    _Float16* __restrict__ w2T)
{
    if (blockIdx.x < 3072) {
        int i = blockIdx.x * 256 + threadIdx.x;
        if (i < 524288) {                        // x: 64rb*8kt*1024 chunks
            int tile = i >> 10, cidx = i & 1023;
            int row = cidx >> 3, c = cidx & 7;
            int rb = tile >> 3, kt = tile & 7;
            int gk = kt * 64 + ((c ^ (row & 7)) << 3);
            *(f16x8*)(xh + (size_t)i * 8) = cvt8(x + (size_t)(rb * 128 + row) * DD + gk);
        } else {
            int j = i - 524288;                  // sw: 32cb*8kt*1024 chunks
            if (j < 262144) {
                int tile = j >> 10, cidx = j & 1023;
                int col = cidx >> 3, c = cidx & 7;
                int cb = tile >> 3, kt = tile & 7;
                int tt = col >> 6, node = col & 63;
                f16x8 h = (f16x8)(_Float16)0.f;
                if (node < NN) {
                    int gk = kt * 64 + ((c ^ (col & 7)) << 3);
                    h = cvt8(sw + (size_t)((cb * 2 + tt) * NN + node) * DD + gk);
                }
                *(f16x8*)(swh + (size_t)j * 8) = h;
            }
        }
    } else {
        int row  = (blockIdx.x - 3072) * 4 + (threadIdx.x >> 6);  // t*64 + l
        int lane = threadIdx.x & 63;
        int t = row >> 6, l = row & 63;
        const float* src = leaf_logits + (size_t)row * CC;
        float v0 = (lane < CC)      ? src[lane]      : -1e30f;
        float v1 = (lane + 64 < CC) ? src[lane + 64] : -1e30f;
        float m = fmaxf(v0, v1);
#pragma unroll
        for (int off = 32; off > 0; off >>= 1)
            m = fmaxf(m, __shfl_down(m, off, 64));
        m = __shfl(m, 0, 64);
        float e0 = (lane < CC)      ? __expf(v0 - m) : 0.f;
        float e1 = (lane + 64 < CC) ? __expf(v1 - m) : 0.f;
        float s = e0 + e1;
#pragma unroll
        for (int off = 32; off > 0; off >>= 1)
            s += __shfl_down(s, off, 64);
        s = __shfl(s, 0, 64);
        float scale = tree_w[t] / s;
        _Float16* base = w2T + (size_t)t * CPAD * LL;
#define LSWZ(c) ((((l >> 3) ^ ((c) & 7)) << 3) | (l & 7))
        if (lane < CC)      base[(size_t)lane * LL + LSWZ(lane)]               = (_Float16)(e0 * scale);
        if (lane + 64 < CC) base[(size_t)(lane + 64) * LL + LSWZ(lane + 64)]   = (_Float16)(e1 * scale);
        if (lane < CPAD - CC) base[(size_t)(CC + lane) * LL + LSWZ(CC + lane)] = (_Float16)0.f;
#undef LSWZ
    }
}

// ---------------------------------------------------------------------------
// Phase A: GEMM1 with 2 row-tiles per block (256 rows x 128 cols = 2 trees),
// BK=64, 8 iters; 64 MFMA/wave per barrier pair (2x R8's ratio).
// grid = (32 rb-pairs, 32 colblocks); 256 threads (4 waves 2x2 per rb).
// Epilogue: R8's dual-tree epilogue run per rb, aliasing the 48KB staging.
// ---------------------------------------------------------------------------
#define A_SMEM 49152
__global__ __launch_bounds__(256) void gemm1_kernel(
    const _Float16* __restrict__ xh,
    const _Float16* __restrict__ swh,
    const float* __restrict__ sb,
    _Float16* __restrict__ lp_ws)
{
    __shared__ __align__(16) char smem[A_SMEM];
    _Float16* xsA = (_Float16*)smem;             // [128][64] staging rbA
    _Float16* xsB = (_Float16*)(smem + 16384);   // [128][64] staging rbB
    _Float16* wl  = (_Float16*)(smem + 32768);   // [128][64] staging W
    _Float16* dec = (_Float16*)smem;             // [128 col][130] logits (alias)
    _Float16* lpl = (_Float16*)smem;             // [2][128][8 slot][8] (alias)

    const int tid  = threadIdx.x;
    const int lane = tid & 63;
    const int wid  = tid >> 6;
    const int wy   = wid >> 1;
    const int wx   = wid & 1;
    const int quad = lane >> 4;
    const int l15  = lane & 15;
    const int cb   = blockIdx.y;

    float bias_v[4];
    {
        int mytree = cb * 2 + wx;
#pragma unroll
        for (int ni = 0; ni < 4; ++ni) {
            int nd = 16 * ni + l15;
            bias_v[ni] = (nd < NN) ? sb[mytree * NN + nd] : 0.f;
        }
    }

    floatx4 acc[2][4][4];
#pragma unroll
    for (int rb = 0; rb < 2; ++rb)
#pragma unroll
        for (int i = 0; i < 4; ++i)
#pragma unroll
            for (int j = 0; j < 4; ++j) acc[rb][i][j] = (floatx4)0.f;

    const _Float16* xtileA = xh + (size_t)(blockIdx.x * 2)     * 8 * 8192;
    const _Float16* xtileB = xh + (size_t)(blockIdx.x * 2 + 1) * 8 * 8192;
    const _Float16* wtile  = swh + (size_t)cb * 8 * 8192;

    for (int kt = 0; kt < 8; ++kt) {
        __syncthreads();   // previous tile's frag reads done
#pragma unroll
        for (int j = 0; j < 4; ++j) {   // fully coalesced 1KB per instr
            int off = (j * 256 + tid) * 8;      // f16 offset within 16KB tile
            gl_lds16(xtileA + kt * 8192 + off, smem +         off * 2);
            gl_lds16(xtileB + kt * 8192 + off, smem + 16384 + off * 2);
            gl_lds16(wtile  + kt * 8192 + off, smem + 32768 + off * 2);
        }
        __syncthreads();   // vmcnt(0) drain: tiles visible
#pragma unroll
        for (int ks = 0; ks < 2; ++ks) {
            f16x8 afA[4], afB[4], bf[4];
#pragma unroll
            for (int mi = 0; mi < 4; ++mi) {
                int r = 64 * wy + 16 * mi + l15;
                int so = r * 64 + ((((ks << 2) | quad) ^ (r & 7)) << 3);
                afA[mi] = *(const f16x8*)&xsA[so];
                afB[mi] = *(const f16x8*)&xsB[so];
            }
#pragma unroll
            for (int ni = 0; ni < 4; ++ni) {
                int r = 64 * wx + 16 * ni + l15;
                bf[ni] = *(const f16x8*)&wl[r * 64 + ((((ks << 2) | quad) ^ (r & 7)) << 3)];
            }
#pragma unroll
            for (int mi = 0; mi < 4; ++mi)
#pragma unroll
                for (int ni = 0; ni < 4; ++ni) {
                    acc[0][mi][ni] = __builtin_amdgcn_mfma_f32_16x16x32_f16(
                        afA[mi], bf[ni], acc[0][mi][ni], 0, 0, 0);
                    acc[1][mi][ni] = __builtin_amdgcn_mfma_f32_16x16x32_f16(
                        afB[mi], bf[ni], acc[1][mi][ni], 0, 0, 0);
                }
        }
    }

    // ---------------- epilogue: per row-tile, R8 pattern ----------------
    for (int rb = 0; rb < 2; ++rb) {
        __syncthreads();   // staging/frag reads or prev lpl reads done

        // biased logits -> dec[col][row], f16x4 packed stores
#pragma unroll
        for (int mi = 0; mi < 4; ++mi) {
            int r0 = 64 * wy + 16 * mi + 4 * quad;
#pragma unroll
            for (int ni = 0; ni < 4; ++ni) {
                int col = 64 * wx + 16 * ni + l15;
                f16x4 v;
#pragma unroll
                for (int r = 0; r < 4; ++r)
                    v[r] = (_Float16)(acc[rb][mi][ni][r] + bias_v[ni]);
                *(f16x4*)&dec[col * 130 + r0] = v;
            }
        }
        __syncthreads();

        // leafprob: thread = (tree tt, row lrow); fast sigmoid inline
        const int tt   = tid >> 7;
        const int lrow = tid & 127;
        const int tb   = tt * 64;
        f16x8 lpreg[8];
        {
#define SIG(n) fsig((float)dec[(tb + (n)) * 130 + lrow])
            float d0 = SIG(0);
#pragma unroll
            for (int h = 0; h < 2; ++h) {
                float p1 = h ? d0 : 1.f - d0;
                float d1 = SIG(1 + h);
#pragma unroll
                for (int b8 = 0; b8 < 4; ++b8) {
                    int i4 = b8 >> 1, i3 = b8 & 1;
                    float p2 = p1 * (i4 ? d1 : 1.f - d1);
                    float d2 = SIG(3 + 2 * h + i4);
                    float p3 = p2 * (i3 ? d2 : 1.f - d2);
                    float d3 = SIG(7 + 4 * h + b8);
                    f16x8 blk;
#pragma unroll
                    for (int i2 = 0; i2 < 2; ++i2) {
                        float p4 = p3 * (i2 ? d3 : 1.f - d3);
                        float d4 = SIG(15 + 8 * h + 2 * b8 + i2);
#pragma unroll
                        for (int i1 = 0; i1 < 2; ++i1) {
                            float p5 = p4 * (i1 ? d4 : 1.f - d4);
                            float d5 = SIG(31 + 16 * h + 4 * b8 + 2 * i2 + i1);
                            blk[i2 * 4 + i1 * 2 + 0] = (_Float16)(p5 * (1.f - d5));
                            blk[i2 * 4 + i1 * 2 + 1] = (_Float16)(p5 * d5);
                        }
                    }
                    lpreg[h * 4 + b8] = blk;
                }
            }
#undef SIG
        }
        __syncthreads();   // all dec reads done -> lpl aliases it

#pragma unroll
        for (int q = 0; q < 8; ++q)
            *(f16x8*)&lpl[tt * 8192 + lrow * 64 + ((q ^ (lrow & 7)) << 3)] = lpreg[q];
        __syncthreads();

        // cooperative LINEAR store keeping swizzled chunk order
        const int rloc0 = (blockIdx.x * 2 + rb) * 128;
#pragma unroll
        for (int k = 0; k < 8; ++k) {
            int idx = k * 256 + tid;          // 0..2047
            int t2 = idx >> 10, rem = idx & 1023;
            int row = rem >> 3, cq = rem & 7;
            f16x8 v = *(const f16x8*)&lpl[t2 * 8192 + row * 64 + cq * 8];
            *(f16x8*)(lp_ws + ((size_t)(cb * 2 + t2) * BB + rloc0 + row) * 64 + cq * 8) = v;
        }
    }
}

// ---------------------------------------------------------------------------
// Phase B (fused gemm2+reduce): grid 256 blocks x 512 threads (8 waves).
// Block = 32 rows x 112 cols; trees split 8-ways across waves (8 each).
// A/B frags direct from global (swizzle folded into address), manual 2-stage
// register pipeline for load ILP. 2-phase LDS reduce -> direct store to out.
// ---------------------------------------------------------------------------
#define RSTR 113                 // padded row stride (floats) in reduce region
#define RREG (32 * RSTR)         // 3616 floats per region
__global__ __launch_bounds__(512, 2) void gemm2_kernel(
    const _Float16* __restrict__ lp_ws,   // [64][8192][64] swizzled chunks
    const _Float16* __restrict__ w2T,     // [64][112][64] swizzled chunks
    float* __restrict__ out)              // [8192][100]
{
    __shared__ float red[4 * RREG];       // 57856 B

    const int tid  = threadIdx.x;
    const int lane = tid & 63;
    const int wv   = tid >> 6;            // 0..7
    const int quad = lane >> 4;
    const int l15  = lane & 15;
    const int r0   = blockIdx.x * 32;
    const int t0   = wv * 8;              // this wave's first tree

    floatx4 oacc[2][7];
#pragma unroll
    for (int mi = 0; mi < 2; ++mi)
#pragma unroll
        for (int ni = 0; ni < 7; ++ni) oacc[mi][ni] = (floatx4)0.f;

    // swizzled chunk offset per ks (row&7 == c&7 == l15&7 here)
    const int sw0 = ((0 | quad) ^ (l15 & 7)) << 3;
    const int sw1 = ((4 | quad) ^ (l15 & 7)) << 3;
    const _Float16* aBase = lp_ws + ((size_t)t0 * BB + r0 + l15) * 64;
    const _Float16* bBase = w2T + (size_t)t0 * CPAD * LL + (size_t)l15 * 64;

    f16x8 ab[2][2], bb[2][7];
    // step s = t8*2 + ks  (16 steps); load step into buf, mfma previous
#define LOADS(s, buf)                                                          \
    {                                                                          \
        int t8 = (s) >> 1;                                                     \
        int sw = ((s) & 1) ? sw1 : sw0;                                        \
        const _Float16* ap = aBase + (size_t)t8 * (BB * 64);                   \
        const _Float16* bp = bBase + (size_t)t8 * (CPAD * LL);                 \
        ab[buf][0] = *(const f16x8*)(ap + sw);                                 \
        ab[buf][1] = *(const f16x8*)(ap + 16 * 64 + sw);                       \
        _Pragma("unroll")                                                      \
        for (int ni = 0; ni < 7; ++ni)                                         \
            bb[buf][ni] = *(const f16x8*)(bp + ni * 16 * 64 + sw);             \
    }
#define MFMAS(buf)                                                             \
    {                                                                          \
        _Pragma("unroll")                                                      \
        for (int mi = 0; mi < 2; ++mi)                                         \
            _Pragma("unroll")                                                  \
            for (int ni = 0; ni < 7; ++ni)                                     \
                oacc[mi][ni] = __builtin_amdgcn_mfma_f32_16x16x32_f16(         \
                    ab[buf][mi], bb[buf][ni], oacc[mi][ni], 0, 0, 0);          \
    }
    LOADS(0, 0)
#pragma unroll
    for (int s = 0; s < 15; ++s) {
        LOADS(s + 1, (s + 1) & 1)
        MFMAS(s & 1)
    }
    MFMAS(1)
#undef LOADS
#undef MFMAS

    // phase 1: waves 4..7 write partials to regions 0..3
    if (wv >= 4) {
        float* rg = &red[(wv - 4) * RREG];
#pragma unroll
        for (int mi = 0; mi < 2; ++mi)
#pragma unroll
            for (int ni = 0; ni < 7; ++ni)
#pragma unroll
                for (int r = 0; r < 4; ++r)
                    rg[(16 * mi + 4 * quad + r) * RSTR + 16 * ni + l15] = oacc[mi][ni][r];
    }
    __syncthreads();
    // phase 2: waves 0..3 add their acc into region wv
    if (wv < 4) {
        float* rg = &red[wv * RREG];
#pragma unroll
        for (int mi = 0; mi < 2; ++mi)
#pragma unroll
            for (int ni = 0; ni < 7; ++ni)
#pragma unroll
                for (int r = 0; r < 4; ++r)
                    rg[(16 * mi + 4 * quad + r) * RSTR + 16 * ni + l15] += oacc[mi][ni][r];
    }
    __syncthreads();
    // final: sum 4 regions, store. thread -> (row = tid>>4, cols k*16+(tid&15))
    {
        int row = tid >> 4, c16 = tid & 15;
#pragma unroll
        for (int k = 0; k < 7; ++k) {
            int col = k * 16 + c16;
            float s = 0.f;
#pragma unroll
            for (int g = 0; g < 4; ++g)
                s += red[g * RREG + row * RSTR + col];
            if (col < CC)
                out[(size_t)(r0 + row) * CC + col] = s;
        }
    }
}

// ---------------------------------------------------------------------------
extern "C" void kernel_launch(void* const* d_in, const int* in_sizes, int n_in,
                              void* d_out, int out_size, void* d_ws, size_t ws_size,
                              hipStream_t stream) {
    const float* x  = (const float*)d_in[0];   // [8192][512]
    const float* sw = (const float*)d_in[1];   // [64][63][512]
    const float* sb = (const float*)d_in[2];   // [64][63]
    const float* ll = (const float*)d_in[3];   // [64][64][100]
    const float* tw = (const float*)d_in[4];   // [64]
    float* out = (float*)d_out;                // [8192][100]
    _Float16* xh  = (_Float16*)((char*)d_ws + XH_WS);
    _Float16* swh = (_Float16*)((char*)d_ws + SWH_WS);
    _Float16* w2T = (_Float16*)((char*)d_ws + W2T_WS);
    _Float16* lp  = (_Float16*)((char*)d_ws + LP_WS);

    prep_kernel<<<dim3(4096), 256, 0, stream>>>(x, sw, ll, tw, xh, swh, w2T);
    gemm1_kernel<<<dim3(32, 32), 256, 0, stream>>>(xh, swh, sb, lp);
    gemm2_kernel<<<dim3(256), 512, 0, stream>>>(lp, w2T, out);
}

// Round 10
// 171.455 us; speedup vs baseline: 1.0976x; 1.0976x over previous
//
#include <hip/hip_runtime.h>

#define TREES 64
#define NN 63        // internal nodes per tree
#define LL 64        // leaves per tree
#define CC 100       // classes
#define CPAD 112     // classes padded to 7*16
#define DD 512       // feature dim
#define BB 8192      // batch

typedef __attribute__((ext_vector_type(8))) _Float16 f16x8;
typedef __attribute__((ext_vector_type(4))) _Float16 f16x4;
typedef __attribute__((ext_vector_type(4))) float floatx4;

// ---- workspace layout (bytes); ws_size ~= 256 MiB ----
#define XH_WS   0            // x  tiled: [64 rb][8 kt][128 row][8 c][8] f16 = 8 MB
#define SWH_WS  8388608      // sw tiled: [32 cb][8 kt][128 col][8 c][8] f16 = 4 MB
#define W2T_WS  12582912     // [64 t][112 c][64 l] f16 (chunk-swizzled) = 0.92 MB
#define LP_WS   13500416     // [64 t][8192 row][64 l] f16 (chunk-swizzled) = 67 MB

__device__ __forceinline__ void gl_lds16(const _Float16* g, char* lds) {
    __builtin_amdgcn_global_load_lds(
        (const __attribute__((address_space(1))) unsigned int*)g,
        (__attribute__((address_space(3))) unsigned int*)lds, 16, 0, 0);
}

__device__ __forceinline__ f16x8 cvt8(const float* s) {
    float4 a = *(const float4*)s, b = *(const float4*)(s + 4);
    f16x8 h;
    h[0]=(_Float16)a.x; h[1]=(_Float16)a.y; h[2]=(_Float16)a.z; h[3]=(_Float16)a.w;
    h[4]=(_Float16)b.x; h[5]=(_Float16)b.y; h[6]=(_Float16)b.z; h[7]=(_Float16)b.w;
    return h;
}

// fast sigmoid: rcp is 1-ulp accurate; result rounds to f16 anyway
__device__ __forceinline__ float fsig(float x) {
    return __builtin_amdgcn_rcpf(1.f + __expf(-x));
}

// ---------------------------------------------------------------------------
// Prep (merged): blocks 0..3071 tile+convert x/sw; blocks 3072..4095 build
// w2T[t][c][l'] with leaf chunk pre-swizzled (l' = ((l>>3)^(c&7))*8 + (l&7)).
// ---------------------------------------------------------------------------
__global__ __launch_bounds__(256) void prep_kernel(
    const float* __restrict__ x, const float* __restrict__ sw,
    const float* __restrict__ leaf_logits, const float* __restrict__ tree_w,
    _Float16* __restrict__ xh, _Float16* __restrict__ swh,
    _Float16* __restrict__ w2T)
{
    if (blockIdx.x < 3072) {
        int i = blockIdx.x * 256 + threadIdx.x;
        if (i < 524288) {                        // x: 64rb*8kt*1024 chunks
            int tile = i >> 10, cidx = i & 1023;
            int row = cidx >> 3, c = cidx & 7;
            int rb = tile >> 3, kt = tile & 7;
            int gk = kt * 64 + ((c ^ (row & 7)) << 3);
            *(f16x8*)(xh + (size_t)i * 8) = cvt8(x + (size_t)(rb * 128 + row) * DD + gk);
        } else {
            int j = i - 524288;                  // sw: 32cb*8kt*1024 chunks
            if (j < 262144) {
                int tile = j >> 10, cidx = j & 1023;
                int col = cidx >> 3, c = cidx & 7;
                int cb = tile >> 3, kt = tile & 7;
                int tt = col >> 6, node = col & 63;
                f16x8 h = (f16x8)(_Float16)0.f;
                if (node < NN) {
                    int gk = kt * 64 + ((c ^ (col & 7)) << 3);
                    h = cvt8(sw + (size_t)((cb * 2 + tt) * NN + node) * DD + gk);
                }
                *(f16x8*)(swh + (size_t)j * 8) = h;
            }
        }
    } else {
        int row  = (blockIdx.x - 3072) * 4 + (threadIdx.x >> 6);  // t*64 + l
        int lane = threadIdx.x & 63;
        int t = row >> 6, l = row & 63;
        const float* src = leaf_logits + (size_t)row * CC;
        float v0 = (lane < CC)      ? src[lane]      : -1e30f;
        float v1 = (lane + 64 < CC) ? src[lane + 64] : -1e30f;
        float m = fmaxf(v0, v1);
#pragma unroll
        for (int off = 32; off > 0; off >>= 1)
            m = fmaxf(m, __shfl_down(m, off, 64));
        m = __shfl(m, 0, 64);
        float e0 = (lane < CC)      ? __expf(v0 - m) : 0.f;
        float e1 = (lane + 64 < CC) ? __expf(v1 - m) : 0.f;
        float s = e0 + e1;
#pragma unroll
        for (int off = 32; off > 0; off >>= 1)
            s += __shfl_down(s, off, 64);
        s = __shfl(s, 0, 64);
        float scale = tree_w[t] / s;
        _Float16* base = w2T + (size_t)t * CPAD * LL;
#define LSWZ(c) ((((l >> 3) ^ ((c) & 7)) << 3) | (l & 7))
        if (lane < CC)      base[(size_t)lane * LL + LSWZ(lane)]               = (_Float16)(e0 * scale);
        if (lane + 64 < CC) base[(size_t)(lane + 64) * LL + LSWZ(lane + 64)]   = (_Float16)(e1 * scale);
        if (lane < CPAD - CC) base[(size_t)(CC + lane) * LL + LSWZ(CC + lane)] = (_Float16)0.f;
#undef LSWZ
    }
}

// ---------------------------------------------------------------------------
// Phase A: GEMM1 (128 rows x 128 cols[=2 trees], BK=64, 8 iters) + epilogue
// leafprob -> lp direct to ws (swizzle folded into store address).
// grid = (64 rowblocks, 32 colblocks); 256 threads (4 waves 2x2).
// Exact R8 K-loop (proven 69.6 us / 4 blocks/CU); epilogue trimmed:
// no lpl LDS round-trip, 2 fewer barriers, rcp-based sigmoid.
// ---------------------------------------------------------------------------
#define A_SMEM 33280
__global__ __launch_bounds__(256, 4) void gemm1_kernel(
    const _Float16* __restrict__ xh,
    const _Float16* __restrict__ swh,
    const float* __restrict__ sb,
    _Float16* __restrict__ lp_ws)
{
    __shared__ __align__(16) char smem[A_SMEM];
    _Float16* xs  = (_Float16*)smem;             // [128][64] staging
    _Float16* wl  = (_Float16*)(smem + 16384);   // [128][64] staging
    _Float16* dec = (_Float16*)smem;             // [128 col][130] logits (alias)

    const int tid  = threadIdx.x;
    const int lane = tid & 63;
    const int wid  = tid >> 6;
    const int wy   = wid >> 1;
    const int wx   = wid & 1;
    const int quad = lane >> 4;
    const int l15  = lane & 15;
    const int rb   = blockIdx.x;
    const int cb   = blockIdx.y;

    float bias_v[4];
    {
        int mytree = cb * 2 + wx;
#pragma unroll
        for (int ni = 0; ni < 4; ++ni) {
            int nd = 16 * ni + l15;
            bias_v[ni] = (nd < NN) ? sb[mytree * NN + nd] : 0.f;
        }
    }

    floatx4 acc[4][4];
#pragma unroll
    for (int i = 0; i < 4; ++i)
#pragma unroll
        for (int j = 0; j < 4; ++j) acc[i][j] = (floatx4)0.f;

    const _Float16* xtile = xh + (size_t)rb * 8 * 8192;
    const _Float16* wtile = swh + (size_t)cb * 8 * 8192;

    for (int kt = 0; kt < 8; ++kt) {
        __syncthreads();   // previous tile's frag reads done
#pragma unroll
        for (int j = 0; j < 4; ++j) {   // fully coalesced 1KB per instr
            gl_lds16(xtile + kt * 8192 + j * 2048 + wid * 512 + lane * 8,
                     smem + j * 4096 + wid * 1024);
            gl_lds16(wtile + kt * 8192 + j * 2048 + wid * 512 + lane * 8,
                     smem + 16384 + j * 4096 + wid * 1024);
        }
        __syncthreads();   // vmcnt(0) drain: tile visible
#pragma unroll
        for (int ks = 0; ks < 2; ++ks) {
            f16x8 af[4], bf[4];
#pragma unroll
            for (int mi = 0; mi < 4; ++mi) {
                int r = 64 * wy + 16 * mi + l15;
                af[mi] = *(const f16x8*)&xs[r * 64 + ((((ks << 2) | quad) ^ (r & 7)) << 3)];
            }
#pragma unroll
            for (int ni = 0; ni < 4; ++ni) {
                int r = 64 * wx + 16 * ni + l15;
                bf[ni] = *(const f16x8*)&wl[r * 64 + ((((ks << 2) | quad) ^ (r & 7)) << 3)];
            }
#pragma unroll
            for (int mi = 0; mi < 4; ++mi)
#pragma unroll
                for (int ni = 0; ni < 4; ++ni)
                    acc[mi][ni] = __builtin_amdgcn_mfma_f32_16x16x32_f16(
                        af[mi], bf[ni], acc[mi][ni], 0, 0, 0);
        }
    }
    __syncthreads();   // staging dead -> dec aliases it

    // biased logits -> dec[col][row], f16x4 packed stores
#pragma unroll
    for (int mi = 0; mi < 4; ++mi) {
        int r0 = 64 * wy + 16 * mi + 4 * quad;
#pragma unroll
        for (int ni = 0; ni < 4; ++ni) {
            int col = 64 * wx + 16 * ni + l15;
            f16x4 v;
#pragma unroll
            for (int r = 0; r < 4; ++r)
                v[r] = (_Float16)(acc[mi][ni][r] + bias_v[ni]);
            *(f16x4*)&dec[col * 130 + r0] = v;
        }
    }
    __syncthreads();

    // leafprob: thread = (tree tt, row lrow); fast sigmoid inline;
    // direct swizzled store to lp_ws (no LDS round-trip, no more barriers)
    const int tt   = tid >> 7;
    const int lrow = tid & 127;
    const int tb   = tt * 64;
    _Float16* lpo = lp_ws + ((size_t)(cb * 2 + tt) * BB + blockIdx.x * 128 + lrow) * 64;
    {
#define SIG(n) fsig((float)dec[(tb + (n)) * 130 + lrow])
        float d0 = SIG(0);
#pragma unroll
        for (int h = 0; h < 2; ++h) {
            float p1 = h ? d0 : 1.f - d0;
            float d1 = SIG(1 + h);
#pragma unroll
            for (int b8 = 0; b8 < 4; ++b8) {
                int i4 = b8 >> 1, i3 = b8 & 1;
                float p2 = p1 * (i4 ? d1 : 1.f - d1);
                float d2 = SIG(3 + 2 * h + i4);
                float p3 = p2 * (i3 ? d2 : 1.f - d2);
                float d3 = SIG(7 + 4 * h + b8);
                f16x8 blk;
#pragma unroll
                for (int i2 = 0; i2 < 2; ++i2) {
                    float p4 = p3 * (i2 ? d3 : 1.f - d3);
                    float d4 = SIG(15 + 8 * h + 2 * b8 + i2);
#pragma unroll
                    for (int i1 = 0; i1 < 2; ++i1) {
                        float p5 = p4 * (i1 ? d4 : 1.f - d4);
                        float d5 = SIG(31 + 16 * h + 4 * b8 + 2 * i2 + i1);
                        blk[i2 * 4 + i1 * 2 + 0] = (_Float16)(p5 * (1.f - d5));
                        blk[i2 * 4 + i1 * 2 + 1] = (_Float16)(p5 * d5);
                    }
                }
                int q = h * 4 + b8;
                *(f16x8*)(lpo + ((q ^ (lrow & 7)) << 3)) = blk;
            }
        }
#undef SIG
    }
}

// ---------------------------------------------------------------------------
// Phase B (fused gemm2+reduce): grid 256 blocks x 512 threads (8 waves).
// Block = 32 rows x 112 cols; trees split 8-ways across waves (8 each).
// A/B frags direct from global (swizzle folded into address), manual 2-stage
// register pipeline for load ILP. 2-phase LDS reduce -> direct store to out.
// ---------------------------------------------------------------------------
#define RSTR 113                 // padded row stride (floats) in reduce region
#define RREG (32 * RSTR)         // 3616 floats per region
__global__ __launch_bounds__(512, 2) void gemm2_kernel(
    const _Float16* __restrict__ lp_ws,   // [64][8192][64] swizzled chunks
    const _Float16* __restrict__ w2T,     // [64][112][64] swizzled chunks
    float* __restrict__ out)              // [8192][100]
{
    __shared__ float red[4 * RREG];       // 57856 B

    const int tid  = threadIdx.x;
    const int lane = tid & 63;
    const int wv   = tid >> 6;            // 0..7
    const int quad = lane >> 4;
    const int l15  = lane & 15;
    const int r0   = blockIdx.x * 32;
    const int t0   = wv * 8;              // this wave's first tree

    floatx4 oacc[2][7];
#pragma unroll
    for (int mi = 0; mi < 2; ++mi)
#pragma unroll
        for (int ni = 0; ni < 7; ++ni) oacc[mi][ni] = (floatx4)0.f;

    // swizzled chunk offset per ks (row&7 == c&7 == l15&7 here)
    const int sw0 = ((0 | quad) ^ (l15 & 7)) << 3;
    const int sw1 = ((4 | quad) ^ (l15 & 7)) << 3;
    const _Float16* aBase = lp_ws + ((size_t)t0 * BB + r0 + l15) * 64;
    const _Float16* bBase = w2T + (size_t)t0 * CPAD * LL + (size_t)l15 * 64;

    f16x8 ab[2][2], bb[2][7];
    // step s = t8*2 + ks  (16 steps); load step into buf, mfma previous
#define LOADS(s, buf)                                                          \
    {                                                                          \
        int t8 = (s) >> 1;                                                     \
        int sw = ((s) & 1) ? sw1 : sw0;                                        \
        const _Float16* ap = aBase + (size_t)t8 * (BB * 64);                   \
        const _Float16* bp = bBase + (size_t)t8 * (CPAD * LL);                 \
        ab[buf][0] = *(const f16x8*)(ap + sw);                                 \
        ab[buf][1] = *(const f16x8*)(ap + 16 * 64 + sw);                       \
        _Pragma("unroll")                                                      \
        for (int ni = 0; ni < 7; ++ni)                                         \
            bb[buf][ni] = *(const f16x8*)(bp + ni * 16 * 64 + sw);             \
    }
#define MFMAS(buf)                                                             \
    {                                                                          \
        _Pragma("unroll")                                                      \
        for (int mi = 0; mi < 2; ++mi)                                         \
            _Pragma("unroll")                                                  \
            for (int ni = 0; ni < 7; ++ni)                                     \
                oacc[mi][ni] = __builtin_amdgcn_mfma_f32_16x16x32_f16(         \
                    ab[buf][mi], bb[buf][ni], oacc[mi][ni], 0, 0, 0);          \
    }
    LOADS(0, 0)
#pragma unroll
    for (int s = 0; s < 15; ++s) {
        LOADS(s + 1, (s + 1) & 1)
        MFMAS(s & 1)
    }
    MFMAS(1)
#undef LOADS
#undef MFMAS

    // phase 1: waves 4..7 write partials to regions 0..3
    if (wv >= 4) {
        float* rg = &red[(wv - 4) * RREG];
#pragma unroll
        for (int mi = 0; mi < 2; ++mi)
#pragma unroll
            for (int ni = 0; ni < 7; ++ni)
#pragma unroll
                for (int r = 0; r < 4; ++r)
                    rg[(16 * mi + 4 * quad + r) * RSTR + 16 * ni + l15] = oacc[mi][ni][r];
    }
    __syncthreads();
    // phase 2: waves 0..3 add their acc into region wv
    if (wv < 4) {
        float* rg = &red[wv * RREG];
#pragma unroll
        for (int mi = 0; mi < 2; ++mi)
#pragma unroll
            for (int ni = 0; ni < 7; ++ni)
#pragma unroll
                for (int r = 0; r < 4; ++r)
                    rg[(16 * mi + 4 * quad + r) * RSTR + 16 * ni + l15] += oacc[mi][ni][r];
    }
    __syncthreads();
    // final: sum 4 regions, store. thread -> (row = tid>>4, cols k*16+(tid&15))
    {
        int row = tid >> 4, c16 = tid & 15;
#pragma unroll
        for (int k = 0; k < 7; ++k) {
            int col = k * 16 + c16;
            float s = 0.f;
#pragma unroll
            for (int g = 0; g < 4; ++g)
                s += red[g * RREG + row * RSTR + col];
            if (col < CC)
                out[(size_t)(r0 + row) * CC + col] = s;
        }
    }
}

// ---------------------------------------------------------------------------
extern "C" void kernel_launch(void* const* d_in, const int* in_sizes, int n_in,
                              void* d_out, int out_size, void* d_ws, size_t ws_size,
                              hipStream_t stream) {
    const float* x  = (const float*)d_in[0];   // [8192][512]
    const float* sw = (const float*)d_in[1];   // [64][63][512]
    const float* sb = (const float*)d_in[2];   // [64][63]
    const float* ll = (const float*)d_in[3];   // [64][64][100]
    const float* tw = (const float*)d_in[4];   // [64]
    float* out = (float*)d_out;                // [8192][100]
    _Float16* xh  = (_Float16*)((char*)d_ws + XH_WS);
    _Float16* swh = (_Float16*)((char*)d_ws + SWH_WS);
    _Float16* w2T = (_Float16*)((char*)d_ws + W2T_WS);
    _Float16* lp  = (_Float16*)((char*)d_ws + LP_WS);

    prep_kernel<<<dim3(4096), 256, 0, stream>>>(x, sw, ll, tw, xh, swh, w2T);
    gemm1_kernel<<<dim3(64, 32), 256, 0, stream>>>(xh, swh, sb, lp);
    gemm2_kernel<<<dim3(256), 512, 0, stream>>>(lp, w2T, out);
}

// Round 11
// 160.711 us; speedup vs baseline: 1.1709x; 1.0668x over previous
//
#include <hip/hip_runtime.h>

#define TREES 64
#define NN 63        // internal nodes per tree
#define LL 64        // leaves per tree
#define CC 100       // classes
#define CPAD 112     // classes padded to 7*16
#define DD 512       // feature dim
#define BB 8192      // batch

typedef __attribute__((ext_vector_type(8))) _Float16 f16x8;
typedef __attribute__((ext_vector_type(4))) _Float16 f16x4;
typedef __attribute__((ext_vector_type(4))) float floatx4;

// ---- workspace layout (bytes); ws_size ~= 256 MiB ----
#define XH_WS   0            // x  tiled: [64 rb][8 kt][128 row][8 c][8] f16 = 8 MB
#define SWH_WS  8388608      // sw tiled: [32 cb][8 kt][128 col][8 c][8] f16 = 4 MB
#define W2T_WS  12582912     // [64 t][112 c][64 l] f16 (chunk-swizzled) = 0.92 MB
#define LP_WS   13500416     // [64 t][8192 row][64 l] f16 (chunk-swizzled) = 67 MB

__device__ __forceinline__ void gl_lds16(const _Float16* g, char* lds) {
    __builtin_amdgcn_global_load_lds(
        (const __attribute__((address_space(1))) unsigned int*)g,
        (__attribute__((address_space(3))) unsigned int*)lds, 16, 0, 0);
}

__device__ __forceinline__ f16x8 cvt8(const float* s) {
    float4 a = *(const float4*)s, b = *(const float4*)(s + 4);
    f16x8 h;
    h[0]=(_Float16)a.x; h[1]=(_Float16)a.y; h[2]=(_Float16)a.z; h[3]=(_Float16)a.w;
    h[4]=(_Float16)b.x; h[5]=(_Float16)b.y; h[6]=(_Float16)b.z; h[7]=(_Float16)b.w;
    return h;
}

// fast sigmoid: rcp is 1-ulp accurate; result rounds to f16 anyway
// (validated R9/R10: absmax identical to IEEE-div version)
__device__ __forceinline__ float fsig(float x) {
    return __builtin_amdgcn_rcpf(1.f + __expf(-x));
}

// ---------------------------------------------------------------------------
// Prep (merged): blocks 0..3071 tile+convert x/sw; blocks 3072..4095 build
// w2T[t][c][l'] with leaf chunk pre-swizzled (l' = ((l>>3)^(c&7))*8 + (l&7)).
// ---------------------------------------------------------------------------
__global__ __launch_bounds__(256) void prep_kernel(
    const float* __restrict__ x, const float* __restrict__ sw,
    const float* __restrict__ leaf_logits, const float* __restrict__ tree_w,
    _Float16* __restrict__ xh, _Float16* __restrict__ swh,
    _Float16* __restrict__ w2T)
{
    if (blockIdx.x < 3072) {
        int i = blockIdx.x * 256 + threadIdx.x;
        if (i < 524288) {                        // x: 64rb*8kt*1024 chunks
            int tile = i >> 10, cidx = i & 1023;
            int row = cidx >> 3, c = cidx & 7;
            int rb = tile >> 3, kt = tile & 7;
            int gk = kt * 64 + ((c ^ (row & 7)) << 3);
            *(f16x8*)(xh + (size_t)i * 8) = cvt8(x + (size_t)(rb * 128 + row) * DD + gk);
        } else {
            int j = i - 524288;                  // sw: 32cb*8kt*1024 chunks
            if (j < 262144) {
                int tile = j >> 10, cidx = j & 1023;
                int col = cidx >> 3, c = cidx & 7;
                int cb = tile >> 3, kt = tile & 7;
                int tt = col >> 6, node = col & 63;
                f16x8 h = (f16x8)(_Float16)0.f;
                if (node < NN) {
                    int gk = kt * 64 + ((c ^ (col & 7)) << 3);
                    h = cvt8(sw + (size_t)((cb * 2 + tt) * NN + node) * DD + gk);
                }
                *(f16x8*)(swh + (size_t)j * 8) = h;
            }
        }
    } else {
        int row  = (blockIdx.x - 3072) * 4 + (threadIdx.x >> 6);  // t*64 + l
        int lane = threadIdx.x & 63;
        int t = row >> 6, l = row & 63;
        const float* src = leaf_logits + (size_t)row * CC;
        float v0 = (lane < CC)      ? src[lane]      : -1e30f;
        float v1 = (lane + 64 < CC) ? src[lane + 64] : -1e30f;
        float m = fmaxf(v0, v1);
#pragma unroll
        for (int off = 32; off > 0; off >>= 1)
            m = fmaxf(m, __shfl_down(m, off, 64));
        m = __shfl(m, 0, 64);
        float e0 = (lane < CC)      ? __expf(v0 - m) : 0.f;
        float e1 = (lane + 64 < CC) ? __expf(v1 - m) : 0.f;
        float s = e0 + e1;
#pragma unroll
        for (int off = 32; off > 0; off >>= 1)
            s += __shfl_down(s, off, 64);
        s = __shfl(s, 0, 64);
        float scale = tree_w[t] / s;
        _Float16* base = w2T + (size_t)t * CPAD * LL;
#define LSWZ(c) ((((l >> 3) ^ ((c) & 7)) << 3) | (l & 7))
        if (lane < CC)      base[(size_t)lane * LL + LSWZ(lane)]               = (_Float16)(e0 * scale);
        if (lane + 64 < CC) base[(size_t)(lane + 64) * LL + LSWZ(lane + 64)]   = (_Float16)(e1 * scale);
        if (lane < CPAD - CC) base[(size_t)(CC + lane) * LL + LSWZ(CC + lane)] = (_Float16)0.f;
#undef LSWZ
    }
}

// ---------------------------------------------------------------------------
// Phase A: GEMM1 (128 rows x 128 cols[=2 trees], BK=64, 8 iters) + epilogue
// leafprob -> lp to ws via LDS stage + coalesced store (R8-proven pattern).
// grid = (64 rowblocks, 32 colblocks); 256 threads (4 waves 2x2).
// ---------------------------------------------------------------------------
#define A_SMEM 33280
__global__ __launch_bounds__(256, 4) void gemm1_kernel(
    const _Float16* __restrict__ xh,
    const _Float16* __restrict__ swh,
    const float* __restrict__ sb,
    _Float16* __restrict__ lp_ws)
{
    __shared__ __align__(16) char smem[A_SMEM];
    _Float16* xs  = (_Float16*)smem;             // [128][64] staging
    _Float16* wl  = (_Float16*)(smem + 16384);   // [128][64] staging
    _Float16* dec = (_Float16*)smem;             // [128 col][130] logits (alias)
    _Float16* lpl = (_Float16*)smem;             // [2][128][8 slot][8] (alias)

    const int tid  = threadIdx.x;
    const int lane = tid & 63;
    const int wid  = tid >> 6;
    const int wy   = wid >> 1;
    const int wx   = wid & 1;
    const int quad = lane >> 4;
    const int l15  = lane & 15;
    const int rb   = blockIdx.x;
    const int cb   = blockIdx.y;

    float bias_v[4];
    {
        int mytree = cb * 2 + wx;
#pragma unroll
        for (int ni = 0; ni < 4; ++ni) {
            int nd = 16 * ni + l15;
            bias_v[ni] = (nd < NN) ? sb[mytree * NN + nd] : 0.f;
        }
    }

    floatx4 acc[4][4];
#pragma unroll
    for (int i = 0; i < 4; ++i)
#pragma unroll
        for (int j = 0; j < 4; ++j) acc[i][j] = (floatx4)0.f;

    const _Float16* xtile = xh + (size_t)rb * 8 * 8192;
    const _Float16* wtile = swh + (size_t)cb * 8 * 8192;

    for (int kt = 0; kt < 8; ++kt) {
        __syncthreads();   // previous tile's frag reads done
#pragma unroll
        for (int j = 0; j < 4; ++j) {   // fully coalesced 1KB per instr
            gl_lds16(xtile + kt * 8192 + j * 2048 + wid * 512 + lane * 8,
                     smem + j * 4096 + wid * 1024);
            gl_lds16(wtile + kt * 8192 + j * 2048 + wid * 512 + lane * 8,
                     smem + 16384 + j * 4096 + wid * 1024);
        }
        __syncthreads();   // vmcnt(0) drain: tile visible
#pragma unroll
        for (int ks = 0; ks < 2; ++ks) {
            f16x8 af[4], bf[4];
#pragma unroll
            for (int mi = 0; mi < 4; ++mi) {
                int r = 64 * wy + 16 * mi + l15;
                af[mi] = *(const f16x8*)&xs[r * 64 + ((((ks << 2) | quad) ^ (r & 7)) << 3)];
            }
#pragma unroll
            for (int ni = 0; ni < 4; ++ni) {
                int r = 64 * wx + 16 * ni + l15;
                bf[ni] = *(const f16x8*)&wl[r * 64 + ((((ks << 2) | quad) ^ (r & 7)) << 3)];
            }
#pragma unroll
            for (int mi = 0; mi < 4; ++mi)
#pragma unroll
                for (int ni = 0; ni < 4; ++ni)
                    acc[mi][ni] = __builtin_amdgcn_mfma_f32_16x16x32_f16(
                        af[mi], bf[ni], acc[mi][ni], 0, 0, 0);
        }
    }
    __syncthreads();   // staging dead -> dec aliases it

    // biased logits -> dec[col][row], f16x4 packed stores
#pragma unroll
    for (int mi = 0; mi < 4; ++mi) {
        int r0 = 64 * wy + 16 * mi + 4 * quad;
#pragma unroll
        for (int ni = 0; ni < 4; ++ni) {
            int col = 64 * wx + 16 * ni + l15;
            f16x4 v;
#pragma unroll
            for (int r = 0; r < 4; ++r)
                v[r] = (_Float16)(acc[mi][ni][r] + bias_v[ni]);
            *(f16x4*)&dec[col * 130 + r0] = v;
        }
    }
    __syncthreads();

    // leafprob: thread = (tree tt, row lrow); fast sigmoid inline
    const int tt   = tid >> 7;
    const int lrow = tid & 127;
    const int tb   = tt * 64;
    f16x8 lpreg[8];
    {
#define SIG(n) fsig((float)dec[(tb + (n)) * 130 + lrow])
        float d0 = SIG(0);
#pragma unroll
        for (int h = 0; h < 2; ++h) {
            float p1 = h ? d0 : 1.f - d0;
            float d1 = SIG(1 + h);
#pragma unroll
            for (int b8 = 0; b8 < 4; ++b8) {
                int i4 = b8 >> 1, i3 = b8 & 1;
                float p2 = p1 * (i4 ? d1 : 1.f - d1);
                float d2 = SIG(3 + 2 * h + i4);
                float p3 = p2 * (i3 ? d2 : 1.f - d2);
                float d3 = SIG(7 + 4 * h + b8);
                f16x8 blk;
#pragma unroll
                for (int i2 = 0; i2 < 2; ++i2) {
                    float p4 = p3 * (i2 ? d3 : 1.f - d3);
                    float d4 = SIG(15 + 8 * h + 2 * b8 + i2);
#pragma unroll
                    for (int i1 = 0; i1 < 2; ++i1) {
                        float p5 = p4 * (i1 ? d4 : 1.f - d4);
                        float d5 = SIG(31 + 16 * h + 4 * b8 + 2 * i2 + i1);
                        blk[i2 * 4 + i1 * 2 + 0] = (_Float16)(p5 * (1.f - d5));
                        blk[i2 * 4 + i1 * 2 + 1] = (_Float16)(p5 * d5);
                    }
                }
                lpreg[h * 4 + b8] = blk;
            }
        }
#undef SIG
    }
    __syncthreads();   // all dec reads done -> lpl aliases it

#pragma unroll
    for (int q = 0; q < 8; ++q)
        *(f16x8*)&lpl[tt * 8192 + lrow * 64 + ((q ^ (lrow & 7)) << 3)] = lpreg[q];
    __syncthreads();

    // cooperative LINEAR store keeping swizzled chunk order (fully coalesced:
    // 8 threads/row -> 4KB contiguous per k-iter; R10's direct store caused
    // +32MB partial-line write amplification — keep this staged path)
    const int rloc0 = blockIdx.x * 128;
#pragma unroll
    for (int k = 0; k < 8; ++k) {
        int idx = k * 256 + tid;          // 0..2047
        int t2 = idx >> 10, rem = idx & 1023;
        int row = rem >> 3, cq = rem & 7;
        f16x8 v = *(const f16x8*)&lpl[t2 * 8192 + row * 64 + cq * 8];
        *(f16x8*)(lp_ws + ((size_t)(cb * 2 + t2) * BB + rloc0 + row) * 64 + cq * 8) = v;
    }
}

// ---------------------------------------------------------------------------
// Phase B (fused gemm2+reduce): grid 256 blocks x 512 threads (8 waves).
// Block = 32 rows x 112 cols; trees split 8-ways across waves (8 each).
// A/B frags direct from global (swizzle folded into address), manual 2-stage
// register pipeline for load ILP. 2-phase LDS reduce -> direct store to out.
// ---------------------------------------------------------------------------
#define RSTR 113                 // padded row stride (floats) in reduce region
#define RREG (32 * RSTR)         // 3616 floats per region
__global__ __launch_bounds__(512, 2) void gemm2_kernel(
    const _Float16* __restrict__ lp_ws,   // [64][8192][64] swizzled chunks
    const _Float16* __restrict__ w2T,     // [64][112][64] swizzled chunks
    float* __restrict__ out)              // [8192][100]
{
    __shared__ float red[4 * RREG];       // 57856 B

    const int tid  = threadIdx.x;
    const int lane = tid & 63;
    const int wv   = tid >> 6;            // 0..7
    const int quad = lane >> 4;
    const int l15  = lane & 15;
    const int r0   = blockIdx.x * 32;
    const int t0   = wv * 8;              // this wave's first tree

    floatx4 oacc[2][7];
#pragma unroll
    for (int mi = 0; mi < 2; ++mi)
#pragma unroll
        for (int ni = 0; ni < 7; ++ni) oacc[mi][ni] = (floatx4)0.f;

    // swizzled chunk offset per ks (row&7 == c&7 == l15&7 here)
    const int sw0 = ((0 | quad) ^ (l15 & 7)) << 3;
    const int sw1 = ((4 | quad) ^ (l15 & 7)) << 3;
    const _Float16* aBase = lp_ws + ((size_t)t0 * BB + r0 + l15) * 64;
    const _Float16* bBase = w2T + (size_t)t0 * CPAD * LL + (size_t)l15 * 64;

    f16x8 ab[2][2], bb[2][7];
    // step s = t8*2 + ks  (16 steps); load step into buf, mfma previous
#define LOADS(s, buf)                                                          \
    {                                                                          \
        int t8 = (s) >> 1;                                                     \
        int sw = ((s) & 1) ? sw1 : sw0;                                        \
        const _Float16* ap = aBase + (size_t)t8 * (BB * 64);                   \
        const _Float16* bp = bBase + (size_t)t8 * (CPAD * LL);                 \
        ab[buf][0] = *(const f16x8*)(ap + sw);                                 \
        ab[buf][1] = *(const f16x8*)(ap + 16 * 64 + sw);                       \
        _Pragma("unroll")                                                      \
        for (int ni = 0; ni < 7; ++ni)                                         \
            bb[buf][ni] = *(const f16x8*)(bp + ni * 16 * 64 + sw);             \
    }
#define MFMAS(buf)                                                             \
    {                                                                          \
        _Pragma("unroll")                                                      \
        for (int mi = 0; mi < 2; ++mi)                                         \
            _Pragma("unroll")                                                  \
            for (int ni = 0; ni < 7; ++ni)                                     \
                oacc[mi][ni] = __builtin_amdgcn_mfma_f32_16x16x32_f16(         \
                    ab[buf][mi], bb[buf][ni], oacc[mi][ni], 0, 0, 0);          \
    }
    LOADS(0, 0)
#pragma unroll
    for (int s = 0; s < 15; ++s) {
        LOADS(s + 1, (s + 1) & 1)
        MFMAS(s & 1)
    }
    MFMAS(1)
#undef LOADS
#undef MFMAS

    // phase 1: waves 4..7 write partials to regions 0..3
    if (wv >= 4) {
        float* rg = &red[(wv - 4) * RREG];
#pragma unroll
        for (int mi = 0; mi < 2; ++mi)
#pragma unroll
            for (int ni = 0; ni < 7; ++ni)
#pragma unroll
                for (int r = 0; r < 4; ++r)
                    rg[(16 * mi + 4 * quad + r) * RSTR + 16 * ni + l15] = oacc[mi][ni][r];
    }
    __syncthreads();
    // phase 2: waves 0..3 add their acc into region wv
    if (wv < 4) {
        float* rg = &red[wv * RREG];
#pragma unroll
        for (int mi = 0; mi < 2; ++mi)
#pragma unroll
            for (int ni = 0; ni < 7; ++ni)
#pragma unroll
                for (int r = 0; r < 4; ++r)
                    rg[(16 * mi + 4 * quad + r) * RSTR + 16 * ni + l15] += oacc[mi][ni][r];
    }
    __syncthreads();
    // final: sum 4 regions, store. thread -> (row = tid>>4, cols k*16+(tid&15))
    {
        int row = tid >> 4, c16 = tid & 15;
#pragma unroll
        for (int k = 0; k < 7; ++k) {
            int col = k * 16 + c16;
            float s = 0.f;
#pragma unroll
            for (int g = 0; g < 4; ++g)
                s += red[g * RREG + row * RSTR + col];
            if (col < CC)
                out[(size_t)(r0 + row) * CC + col] = s;
        }
    }
}

// ---------------------------------------------------------------------------
extern "C" void kernel_launch(void* const* d_in, const int* in_sizes, int n_in,
                              void* d_out, int out_size, void* d_ws, size_t ws_size,
                              hipStream_t stream) {
    const float* x  = (const float*)d_in[0];   // [8192][512]
    const float* sw = (const float*)d_in[1];   // [64][63][512]
    const float* sb = (const float*)d_in[2];   // [64][63]
    const float* ll = (const float*)d_in[3];   // [64][64][100]
    const float* tw = (const float*)d_in[4];   // [64]
    float* out = (float*)d_out;                // [8192][100]
    _Float16* xh  = (_Float16*)((char*)d_ws + XH_WS);
    _Float16* swh = (_Float16*)((char*)d_ws + SWH_WS);
    _Float16* w2T = (_Float16*)((char*)d_ws + W2T_WS);
    _Float16* lp  = (_Float16*)((char*)d_ws + LP_WS);

    prep_kernel<<<dim3(4096), 256, 0, stream>>>(x, sw, ll, tw, xh, swh, w2T);
    gemm1_kernel<<<dim3(64, 32), 256, 0, stream>>>(xh, swh, sb, lp);
    gemm2_kernel<<<dim3(256), 512, 0, stream>>>(lp, w2T, out);
}